// Round 16
// baseline (1008.249 us; speedup 1.0000x reference)
//
#include <hip/hip_runtime.h>
#include <hip/hip_bf16.h>

#define NB 4
#define NRQ 32768      // per-batch q-side rows  (n*4)
#define NKF 131072     // per-batch feats rows   (n*16)

using u16 = unsigned short;
typedef short bf16x8 __attribute__((ext_vector_type(8)));
typedef float f32x4  __attribute__((ext_vector_type(4)));
typedef u16   u16x8  __attribute__((ext_vector_type(8)));
typedef u16   u16x4  __attribute__((ext_vector_type(4)));

#if defined(__has_builtin)
#  if __has_builtin(__builtin_amdgcn_fdot2_f32_bf16)
#    define HAVE_DOT2 1
#  endif
#endif
#ifndef HAVE_DOT2
#  define HAVE_DOT2 0
#endif

#if HAVE_DOT2
typedef __bf16 bfv2 __attribute__((ext_vector_type(2)));
union bpack { bf16x8 v; bfv2 p[4]; };
__device__ __forceinline__ float dot2(bfv2 a, bfv2 b, float c){
  return __builtin_amdgcn_fdot2_f32_bf16(a, b, c, false);
}
#endif
union vpack  { bf16x8 v; u16 e[8]; };
union vpack4 { u16x4 v; u16 e[4]; };

__device__ __forceinline__ u16 f2b(float f){
  __hip_bfloat16 h = __float2bfloat16(f);   // native cvt, RNE
  return *reinterpret_cast<u16*>(&h);
}
__device__ __forceinline__ float b2f(u16 v){
  return __uint_as_float(((unsigned)v) << 16);
}

#define GLOAD16(g, l) __builtin_amdgcn_global_load_lds( \
    (const __attribute__((address_space(1))) unsigned int*)(g), \
    (__attribute__((address_space(3))) unsigned int*)(l), 16, 0, 0)

// ---------------------------------------------------------------------------
// Weight preconvert fp32 -> bf16 (stacked) + bias stack + stat zero (merged)
// ---------------------------------------------------------------------------
__global__ __launch_bounds__(256) void cvtW_k(
    const float* __restrict__ Wk, const float* __restrict__ Wv,
    const float* __restrict__ Wq, const float* __restrict__ W1,
    const float* __restrict__ W2, u16* __restrict__ wT,
    const float* __restrict__ bk, const float* __restrict__ bv,
    float* __restrict__ bKV, float* __restrict__ stats)
{
  if (blockIdx.x >= 224){
    int i = (blockIdx.x - 224) * 256 + threadIdx.x;
    if (i < 512)       bKV[i] = (i < 256) ? bk[i] : bv[i - 256];
    else if (i < 1536) stats[i - 512] = 0.f;
    return;
  }
  long e = ((long)blockIdx.x * 256 + threadIdx.x) * 8;
  const float* src; long off;
  if      (e < 65536)  { src = Wk; off = e; }
  else if (e < 131072) { src = Wv; off = e - 65536; }
  else if (e < 196608) { src = Wq; off = e - 131072; }
  else if (e < 327680) { src = W1; off = e - 196608; }
  else                 { src = W2; off = e - 327680; }
  float4 f0 = *reinterpret_cast<const float4*>(src + off);
  float4 f1 = *reinterpret_cast<const float4*>(src + off + 4);
  u16x8 p;
  p[0]=f2b(f0.x); p[1]=f2b(f0.y); p[2]=f2b(f0.z); p[3]=f2b(f0.w);
  p[4]=f2b(f1.x); p[5]=f2b(f1.y); p[6]=f2b(f1.z); p[7]=f2b(f1.w);
  *reinterpret_cast<u16x8*>(wT + e) = p;
}

// ---------------------------------------------------------------------------
// GEMM: C[rows x NCH] = A[rows x KD] (bf16 k-contig) * Wb[NCH x KD]^T + bias.
// MODE 0: bf16 C. MODE 1: + per-ch sum/sumsq atomics.
// MODE 3: A reg-staged with per-k BN scale/shift+relu; epilogue
//         out = relu(acc+bias+residT) -> fp32 outF [ch][row].
// MODE 4: A staged from fp32 Afp [KD ch][aStride] (transpose+convert on
//         stage; conflict-free lane-contiguous b16 stores); epilogue = MODE 0.
// ---------------------------------------------------------------------------
template<int MODE, int KD>
__global__ __launch_bounds__(256) void gemm_k(
    const u16* __restrict__ A, long aBatch, int chTiles,
    const u16* __restrict__ Wb, const float* __restrict__ bias,
    u16* __restrict__ outH, long oBatch, int NCH,
    float* __restrict__ statSum, float* __restrict__ statSq,
    const float* __restrict__ xsc, const float* __restrict__ xsh,
    const float* __restrict__ Afp, long afpBatch, long aStride,
    const u16* __restrict__ residT,
    float* __restrict__ outF, long fBatch)
{
  __shared__ __align__(16) char sA[2][16384];
  __shared__ __align__(16) char sB[2][16384];

  const int t = threadIdx.x, lane = t & 63, wid = t >> 6;
  const int wm = wid >> 1, wn = wid & 1;
  const int b = blockIdx.z;

  const int nwg = gridDim.x, orig = blockIdx.x;
  const int qq = nwg >> 3, rr = nwg & 7, xcd = orig & 7, pos = orig >> 3;
  const int wg = (xcd < rr ? xcd * (qq + 1) : rr * (qq + 1) + (xcd - rr) * qq) + pos;
  const int rowT = wg / chTiles, chT = wg % chTiles;

  const u16* Ab = A + (long)b * aBatch + (long)rowT * 128 * KD;
  const u16* Wt = Wb + (long)chT * 128 * KD;
  const int sub = lane >> 3, kc8 = ((lane & 7) ^ sub) * 8;

  f32x4 acc[4][4];
  #pragma unroll
  for (int i = 0; i < 4; ++i)
    #pragma unroll
    for (int j = 0; j < 4; ++j) acc[i][j] = (f32x4){0.f,0.f,0.f,0.f};

  auto STAGE = [&](int buf, int ks){
    const int k0 = ks * 64;
    if constexpr (MODE == 3){
      const int wrow = t >> 1, whalf = t & 1;
      const u16* arow = Ab + (long)wrow * KD + k0 + whalf * 32;
      #pragma unroll
      for (int i = 0; i < 4; ++i){
        u16x8 v = *reinterpret_cast<const u16x8*>(arow + i * 8);
        const int kb = k0 + whalf*32 + i*8;
        float4 s0 = *reinterpret_cast<const float4*>(xsc + kb);
        float4 s1 = *reinterpret_cast<const float4*>(xsc + kb + 4);
        float4 h0 = *reinterpret_cast<const float4*>(xsh + kb);
        float4 h1 = *reinterpret_cast<const float4*>(xsh + kb + 4);
        u16x8 o;
        o[0]=f2b(fmaxf(b2f(v[0])*s0.x+h0.x,0.f));
        o[1]=f2b(fmaxf(b2f(v[1])*s0.y+h0.y,0.f));
        o[2]=f2b(fmaxf(b2f(v[2])*s0.z+h0.z,0.f));
        o[3]=f2b(fmaxf(b2f(v[3])*s0.w+h0.w,0.f));
        o[4]=f2b(fmaxf(b2f(v[4])*s1.x+h1.x,0.f));
        o[5]=f2b(fmaxf(b2f(v[5])*s1.y+h1.y,0.f));
        o[6]=f2b(fmaxf(b2f(v[6])*s1.z+h1.z,0.f));
        o[7]=f2b(fmaxf(b2f(v[7])*s1.w+h1.w,0.f));
        *reinterpret_cast<u16x8*>(
            sA[buf] + ((wrow*128 + whalf*64 + i*16) ^ ((wrow & 7) << 4))) = o;
      }
      #pragma unroll
      for (int i = 0; i < 4; ++i){
        const int chunk = wid * 4 + i;
        GLOAD16(Wt + (long)(chunk*8 + sub)*KD + k0 + kc8, sB[buf] + chunk*1024);
      }
    } else if constexpr (MODE == 4){
      // A from fp32 [KD ch][aStride rows]: lane = channel, wave = row-quad.
      // Store: 64 lanes write contiguous 128B per (i,j) -> conflict-free.
      const int chq = lane;
      const float* qsrc = Afp + (long)b * afpBatch
                        + (long)(k0 + chq) * aStride + (long)rowT * 128 + wid * 32;
      #pragma unroll
      for (int i = 0; i < 8; ++i){
        float4 f = *reinterpret_cast<const float4*>(qsrc + i * 4);
        #pragma unroll
        for (int j = 0; j < 4; ++j){
          const int m = wid*32 + i*4 + j;
          float e = (j == 0) ? f.x : (j == 1) ? f.y : (j == 2) ? f.z : f.w;
          *reinterpret_cast<u16*>(
              sA[buf] + ((m*128 + chq*2) ^ ((m & 7) << 4))) = f2b(e);
        }
      }
      #pragma unroll
      for (int i = 0; i < 4; ++i){
        const int chunk = wid * 4 + i;
        GLOAD16(Wt + (long)(chunk*8 + sub)*KD + k0 + kc8, sB[buf] + chunk*1024);
      }
    } else {
      #pragma unroll
      for (int i = 0; i < 4; ++i){
        const int chunk = wid * 4 + i;
        GLOAD16(Ab + (long)(chunk*8 + sub)*KD + k0 + kc8, sA[buf] + chunk*1024);
        GLOAD16(Wt + (long)(chunk*8 + sub)*KD + k0 + kc8, sB[buf] + chunk*1024);
      }
    }
  };

  constexpr int NT = KD / 64;
  STAGE(0, 0);
  __syncthreads();
  int cur = 0;
  for (int ks = 0; ks < NT; ++ks){
    if (ks + 1 < NT) STAGE(cur ^ 1, ks + 1);
    const char* pA = sA[cur]; const char* pB = sB[cur];
    #pragma unroll
    for (int kk = 0; kk < 2; ++kk){
      bf16x8 af[4], bf[4];
      #pragma unroll
      for (int mi = 0; mi < 4; ++mi){
        int m = wm*64 + mi*16 + (lane & 15);
        af[mi] = *reinterpret_cast<const bf16x8*>(
            pA + ((m*128 + kk*64 + (lane>>4)*16) ^ ((m & 7) << 4)));
      }
      #pragma unroll
      for (int ni = 0; ni < 4; ++ni){
        int c = wn*64 + ni*16 + (lane & 15);
        bf[ni] = *reinterpret_cast<const bf16x8*>(
            pB + ((c*128 + kk*64 + (lane>>4)*16) ^ ((c & 7) << 4)));
      }
      #pragma unroll
      for (int mi = 0; mi < 4; ++mi)
        #pragma unroll
        for (int ni = 0; ni < 4; ++ni)
          acc[mi][ni] = __builtin_amdgcn_mfma_f32_16x16x32_bf16(
              af[mi], bf[ni], acc[mi][ni], 0, 0, 0);
    }
    __syncthreads();
    cur ^= 1;
  }

  int chI[4]; float bv[4];
  #pragma unroll
  for (int ni = 0; ni < 4; ++ni){
    int ch = chT*128 + wn*64 + ni*16 + (lane & 15);
    chI[ni] = ch;
    bv[ni] = bias[ch];
  }
  if (MODE != 3){
    float s[4] = {0,0,0,0}, sq[4] = {0,0,0,0};
    u16* outb = outH + (long)b * oBatch;
    #pragma unroll
    for (int mi = 0; mi < 4; ++mi){
      #pragma unroll
      for (int j = 0; j < 4; ++j){
        const long row = rowT*128 + wm*64 + mi*16 + (lane>>4)*4 + j;
        #pragma unroll
        for (int ni = 0; ni < 4; ++ni){
          float v = acc[mi][ni][j] + bv[ni];
          outb[row * NCH + chI[ni]] = f2b(v);
          if (MODE == 1){ s[ni] += v; sq[ni] += v * v; }
        }
      }
    }
    if (MODE == 1){
      #pragma unroll
      for (int ni = 0; ni < 4; ++ni){
        s[ni]  += __shfl_xor(s[ni], 16);  s[ni]  += __shfl_xor(s[ni], 32);
        sq[ni] += __shfl_xor(sq[ni], 16); sq[ni] += __shfl_xor(sq[ni], 32);
      }
      if (lane < 16){
        #pragma unroll
        for (int ni = 0; ni < 4; ++ni){
          atomicAdd(&statSum[chI[ni]], s[ni]);
          atomicAdd(&statSq[chI[ni]],  sq[ni]);
        }
      }
    }
  } else {
    const u16* rb = residT + (long)b * ((long)NRQ * 256);
    #pragma unroll
    for (int mi = 0; mi < 4; ++mi){
      const int nr0 = rowT*128 + wm*64 + mi*16 + (lane>>4)*4;
      #pragma unroll
      for (int ni = 0; ni < 4; ++ni){
        float4 o;
        o.x = fmaxf(acc[mi][ni][0] + bv[ni] + b2f(rb[(long)(nr0+0)*256 + chI[ni]]), 0.f);
        o.y = fmaxf(acc[mi][ni][1] + bv[ni] + b2f(rb[(long)(nr0+1)*256 + chI[ni]]), 0.f);
        o.z = fmaxf(acc[mi][ni][2] + bv[ni] + b2f(rb[(long)(nr0+2)*256 + chI[ni]]), 0.f);
        o.w = fmaxf(acc[mi][ni][3] + bv[ni] + b2f(rb[(long)(nr0+3)*256 + chI[ni]]), 0.f);
        *reinterpret_cast<float4*>(outF + (long)b*fBatch + (long)chI[ni]*NRQ + nr0) = o;
      }
    }
  }
}

// ---------------------------------------------------------------------------
// Standalone attention: 256 thr = 4 waves = 4 points; wave = point.
// kvB [B][NKF][512] bf16 (k: ch 0-255, v: ch 256-511) read direct from
// global (single-use, L2-streamed). Phase A: lane=(h,kk), dot2 QK^T +
// shuffle softmax -> P in LDS. Phase B: lane -> 4 channels, V global,
// residual gathered from fp32 queries. Tiny LDS -> many blocks/CU.
// ---------------------------------------------------------------------------
__global__ __launch_bounds__(256) void attn_k(
    const u16* __restrict__ kvB, const u16* __restrict__ qT,
    const float* __restrict__ queries, u16* __restrict__ aggT)
{
  __shared__ float sSf[16 * 68];        // [p*4+h][68dw]: [16 kk][4 r]
  const int t = threadIdx.x, lane = t & 63, p = t >> 6;
  const int b = blockIdx.y;
  const long nqg = (long)blockIdx.x * 4 + p;
  const u16* kvb = kvB + ((long)b * NKF + nqg * 16) * 512;

  // residual prefetch: 4 channels/lane from fp32 queries [B][256][NRQ]
  const int c0 = lane * 4;
  float qr[4][4];                       // [cc][r]
  #pragma unroll
  for (int cc = 0; cc < 4; ++cc){
    float4 q4 = *reinterpret_cast<const float4*>(
        queries + ((long)b*256 + c0 + cc) * NRQ + nqg * 4);
    qr[cc][0]=q4.x; qr[cc][1]=q4.y; qr[cc][2]=q4.z; qr[cc][3]=q4.w;
  }

  // ---- phase A: logits + softmax
  {
    const int h = lane >> 4, kk = lane & 15;
    const u16* kr = kvb + kk*512 + h*64;
    const u16* qb = qT + ((long)b*NRQ + nqg*4)*256 + h*64;
    float l[4] = {0.f, 0.f, 0.f, 0.f};
#if HAVE_DOT2
    #pragma unroll
    for (int d8 = 0; d8 < 8; ++d8){
      bpack K8;
      K8.v = *reinterpret_cast<const bf16x8*>(kr + d8*8);
      #pragma unroll
      for (int r = 0; r < 4; ++r){
        bpack Q;
        Q.v = *reinterpret_cast<const bf16x8*>(qb + r*256 + d8*8);
        #pragma unroll
        for (int pi = 0; pi < 4; ++pi) l[r] = dot2(K8.p[pi], Q.p[pi], l[r]);
      }
    }
#else
    #pragma unroll
    for (int d8 = 0; d8 < 8; ++d8){
      vpack K8;
      K8.v = *reinterpret_cast<const bf16x8*>(kr + d8*8);
      #pragma unroll
      for (int r = 0; r < 4; ++r){
        vpack Q;
        Q.v = *reinterpret_cast<const bf16x8*>(qb + r*256 + d8*8);
        #pragma unroll
        for (int e = 0; e < 8; ++e) l[r] = fmaf(b2f(K8.e[e]), b2f(Q.e[e]), l[r]);
      }
    }
#endif
    float4 prob;
    #pragma unroll
    for (int r = 0; r < 4; ++r){
      float x = l[r] * 0.125f;
      float m = x;
      #pragma unroll
      for (int off = 1; off < 16; off <<= 1) m = fmaxf(m, __shfl_xor(m, off));
      float e = __expf(x - m);
      float ssum = e;
      #pragma unroll
      for (int off = 1; off < 16; off <<= 1) ssum += __shfl_xor(ssum, off);
      float pr = e / ssum;
      if (r == 0) prob.x = pr; else if (r == 1) prob.y = pr;
      else if (r == 2) prob.z = pr; else prob.w = pr;
    }
    *reinterpret_cast<float4*>(sSf + (p*4 + h)*68 + kk*4) = prob;
  }
  __syncthreads();

  // ---- phase B: agg = v @ soft^T + residual
  {
    const int h = c0 >> 6;
    const u16* vb = kvb + 256 + c0;
    const float* ss = sSf + (p*4 + h)*68;
    float a[4][4] = {};
    #pragma unroll
    for (int kk = 0; kk < 16; ++kk){
      vpack4 vv;
      vv.v = *reinterpret_cast<const u16x4*>(vb + kk*512);
      float4 sv = *reinterpret_cast<const float4*>(ss + kk*4);
      #pragma unroll
      for (int cc = 0; cc < 4; ++cc){
        float vf = b2f(vv.e[cc]);
        a[0][cc] += sv.x*vf; a[1][cc] += sv.y*vf;
        a[2][cc] += sv.z*vf; a[3][cc] += sv.w*vf;
      }
    }
    u16* ob = aggT + ((long)b*NRQ + nqg*4)*256 + c0;
    #pragma unroll
    for (int r = 0; r < 4; ++r){
      u16x4 pk;
      #pragma unroll
      for (int cc = 0; cc < 4; ++cc) pk[cc] = f2b(a[r][cc] + qr[cc][r]);
      *reinterpret_cast<u16x4*>(ob + r*256) = pk;
    }
  }
}

__global__ void finalize_k(const float* __restrict__ st,
                           const float* __restrict__ gamma,
                           const float* __restrict__ beta,
                           float* __restrict__ out)   // scale[512], shift[512]
{
  int o = blockIdx.x*256 + threadIdx.x;
  const float inv = 1.f / 131072.f;                   // B*N*R
  float mean = st[o] * inv;
  float var  = st[512 + o] * inv - mean*mean;
  float sc   = gamma[o] * rsqrtf(var + 1e-5f);
  out[o]       = sc;
  out[512 + o] = beta[o] - mean * sc;
}

// ---------------------------------------------------------------------------
extern "C" void kernel_launch(void* const* d_in, const int* in_sizes, int n_in,
                              void* d_out, int out_size, void* d_ws, size_t ws_size,
                              hipStream_t stream)
{
  (void)in_sizes; (void)n_in; (void)out_size; (void)ws_size;
  const float* queries = (const float*)d_in[0];
  const float* feats   = (const float*)d_in[1];
  const float* Wq = (const float*)d_in[2];
  const float* bq = (const float*)d_in[3];
  const float* Wk = (const float*)d_in[4];
  const float* bk = (const float*)d_in[5];
  const float* Wv = (const float*)d_in[6];
  const float* bv = (const float*)d_in[7];
  const float* W1 = (const float*)d_in[8];
  const float* b1 = (const float*)d_in[9];
  const float* gamma = (const float*)d_in[10];
  const float* beta  = (const float*)d_in[11];
  const float* W2 = (const float*)d_in[12];
  const float* b2 = (const float*)d_in[13];

  // ws layout (bytes), max 672 MB (< 738 MB proven in R1/R2):
  //   [0, 536.9M)      : kvB bf16 [B][NKF][512]; h1T (134.2M) aliases after attn
  //   [536.9M, 604M)   : qT bf16 [B][NRQ][256]
  //   [604M, 671.1M)   : aggT bf16 [B][NRQ][256]
  //   [671.1M, +8K)    : stats; then wT weights + bKV
  char* ws = (char*)d_ws;
  u16*   kvB   = (u16*)ws;
  u16*   h1T   = (u16*)ws;
  u16*   qT    = (u16*)(ws + 536870912L);
  u16*   aggT  = (u16*)(ws + 603979776L);
  float* stats = (float*)(ws + 671088640L);
  float* scale = stats + 1024;
  float* shift = stats + 1536;
  u16*   wT    = (u16*)(ws + 671096832L);
  u16*   wKV   = wT;                 // 512 x 256
  u16*   wQ    = wT + 131072;        // 256 x 256
  u16*   wW1   = wT + 196608;        // 512 x 256
  u16*   wW2   = wT + 327680;        // 256 x 512
  float* bKV   = (float*)(wT + 458752);

  cvtW_k<<<dim3(230), 256, 0, stream>>>(Wk, Wv, Wq, W1, W2, wT,
                                        bk, bv, bKV, stats);

  // qT = queries^T @ Wq^T + bq (MODE 4: A staged from fp32 queries)
  gemm_k<4, 256><<<dim3(512, 1, NB), 256, 0, stream>>>(
      nullptr, 0, 2, wQ, bq,
      qT, (long)NRQ*256, 256, nullptr, nullptr, nullptr, nullptr,
      queries, (long)256*NRQ, NRQ, nullptr, nullptr, 0);

  // kvB = feats^T @ [Wk;Wv]^T + [bk;bv] (MODE 4: A staged from fp32 feats)
  gemm_k<4, 256><<<dim3(4096, 1, NB), 256, 0, stream>>>(
      nullptr, 0, 4, wKV, bKV,
      kvB, (long)NKF*512, 512, nullptr, nullptr, nullptr, nullptr,
      feats, (long)256*NKF, NKF, nullptr, nullptr, 0);

  // attention -> aggT (residual from fp32 queries)
  attn_k<<<dim3(NKF/64, NB), 256, 0, stream>>>(kvB, qT, queries, aggT);

  // h1 = aggT @ W1^T + b1 -> bf16 + BN stats
  gemm_k<1, 256><<<dim3(1024, 1, NB), 256, 0, stream>>>(
      aggT, (long)NRQ*256, 4, wW1, b1,
      h1T, (long)NRQ*512, 512, stats, stats + 512, nullptr, nullptr,
      nullptr, 0, 0, nullptr, nullptr, 0);

  finalize_k<<<dim3(2), 256, 0, stream>>>(stats, gamma, beta, scale);

  // d_out = relu( relu(bn(h1)) @ W2^T + b2 + aggT ) -> fp32 [B][256][NRQ]
  gemm_k<3, 512><<<dim3(512, 1, NB), 256, 0, stream>>>(
      h1T, (long)NRQ*512, 2, wW2, b2,
      nullptr, 0, 256, nullptr, nullptr, scale, shift,
      nullptr, 0, 0, aggT, (float*)d_out, (long)256*NRQ);
}